// Round 1
// baseline (1798.377 us; speedup 1.0000x reference)
//
#include <hip/hip_runtime.h>
#include <hip/hip_bf16.h>

#define H 192
#define HH (192*192)

// ---------------- CSR construction ----------------

__global__ void hist_kernel(const int* __restrict__ dst, int* __restrict__ counts, int E) {
    int e = blockIdx.x * blockDim.x + threadIdx.x;
    if (e < E) atomicAdd(&counts[dst[e]], 1);
}

__global__ void scan_kernel(const int* __restrict__ counts, int* __restrict__ row_ptr, int n) {
    __shared__ int sh[1024];
    __shared__ int carry_s;
    int tid = threadIdx.x;
    if (tid == 0) carry_s = 0;
    __syncthreads();
    for (int base = 0; base < n; base += 1024) {
        int i = base + tid;
        int v = (i < n) ? counts[i] : 0;
        sh[tid] = v;
        __syncthreads();
        for (int off = 1; off < 1024; off <<= 1) {
            int t = (tid >= off) ? sh[tid - off] : 0;
            __syncthreads();
            sh[tid] += t;
            __syncthreads();
        }
        int carry = carry_s;
        if (i < n) row_ptr[i + 1] = carry + sh[tid];
        __syncthreads();
        if (tid == 1023) carry_s = carry + sh[1023];
        __syncthreads();
    }
    if (tid == 0) row_ptr[0] = 0;
}

__global__ void scatter_kernel(const int* __restrict__ src, const int* __restrict__ dst,
                               const float* __restrict__ w, int* __restrict__ cursor,
                               int* __restrict__ ci, float* __restrict__ cw, int E) {
    int e = blockIdx.x * blockDim.x + threadIdx.x;
    if (e < E) {
        int p = atomicAdd(&cursor[dst[e]], 1);
        ci[p] = src[e];
        cw[p] = w[e];
    }
}

// ---------------- Dense GEMM: C[M x 192] = A[M x 192] @ B[192 x 192] ----------------

#define TILE 64
#define KT 16

__global__ void gemm_kernel(const float* __restrict__ A, const float* __restrict__ B,
                            float* __restrict__ C, int M) {
    __shared__ float As[KT][TILE + 1];
    __shared__ float Bs[KT][TILE + 1];
    int bm = blockIdx.x * TILE;
    int bn = blockIdx.y * TILE;
    int tid = threadIdx.x;          // 0..255
    int tr = tid >> 4, tc = tid & 15;
    float acc[4][4] = {};
    for (int k0 = 0; k0 < H; k0 += KT) {
        for (int i = tid; i < TILE * KT; i += 256) {
            int m = i / KT, kk = i % KT;
            int row = bm + m;
            As[kk][m] = (row < M) ? A[(size_t)row * H + k0 + kk] : 0.f;
        }
        for (int i = tid; i < KT * TILE; i += 256) {
            int kk = i / TILE, nn = i % TILE;
            Bs[kk][nn] = B[(size_t)(k0 + kk) * H + bn + nn];
        }
        __syncthreads();
        #pragma unroll
        for (int kk = 0; kk < KT; ++kk) {
            float a[4], b[4];
            #pragma unroll
            for (int i = 0; i < 4; i++) a[i] = As[kk][tr * 4 + i];
            #pragma unroll
            for (int j = 0; j < 4; j++) b[j] = Bs[kk][tc * 4 + j];
            #pragma unroll
            for (int i = 0; i < 4; i++)
                #pragma unroll
                for (int j = 0; j < 4; j++) acc[i][j] += a[i] * b[j];
        }
        __syncthreads();
    }
    for (int i = 0; i < 4; i++) {
        int row = bm + tr * 4 + i;
        if (row < M) {
            #pragma unroll
            for (int j = 0; j < 4; j++)
                C[(size_t)row * H + bn + tc * 4 + j] = acc[i][j];
        }
    }
}

// ---------------- SpMM: out[v] = epilogue( sum_e w_e * S[src_e] + bias ) ----------------
// mode 0: out = relu(agg + b)
// mode 1: out = (resid + relu(agg + b)) * 0.5

__global__ void spmm_kernel(const float* __restrict__ S, const int* __restrict__ rp,
                            const int* __restrict__ ci, const float* __restrict__ cw,
                            const float* __restrict__ bias, float* __restrict__ out,
                            const float* __restrict__ resid, int mode) {
    int v = blockIdx.x;
    int c = threadIdx.x;            // 0..191
    float acc = bias[c];
    int beg = rp[v], end = rp[v + 1];
    for (int e = beg; e < end; ++e) {
        int s = ci[e];
        float w = cw[e];
        acc += w * S[(size_t)s * H + c];
    }
    acc = fmaxf(acc, 0.f);
    size_t idx = (size_t)v * H + c;
    if (mode == 0) out[idx] = acc;
    else           out[idx] = (resid[idx] + acc) * 0.5f;
}

// ---------------- Output head ----------------

__global__ void gemm_head(const float* __restrict__ A, const float* __restrict__ W,
                          float* __restrict__ S3, int M) {
    int row = blockIdx.x * blockDim.x + threadIdx.x;
    if (row >= M) return;
    float a0 = 0.f, a1 = 0.f, a2 = 0.f;
    for (int k = 0; k < H; k++) {
        float x = A[(size_t)row * H + k];
        a0 += x * W[k * 3 + 0];
        a1 += x * W[k * 3 + 1];
        a2 += x * W[k * 3 + 2];
    }
    S3[row * 3 + 0] = a0;
    S3[row * 3 + 1] = a1;
    S3[row * 3 + 2] = a2;
}

__global__ void spmm_head(const float* __restrict__ S3, const int* __restrict__ rp,
                          const int* __restrict__ ci, const float* __restrict__ cw,
                          const float* __restrict__ b_out, float* __restrict__ coords, int Nv) {
    int v = blockIdx.x * blockDim.x + threadIdx.x;
    if (v >= Nv) return;
    float a0 = b_out[0], a1 = b_out[1], a2 = b_out[2];
    int end = rp[v + 1];
    for (int e = rp[v]; e < end; ++e) {
        int s = ci[e];
        float w = cw[e];
        a0 += w * S3[s * 3 + 0];
        a1 += w * S3[s * 3 + 1];
        a2 += w * S3[s * 3 + 2];
    }
    coords[v * 3 + 0] = a0;
    coords[v * 3 + 1] = a1;
    coords[v * 3 + 2] = a2;
}

// ---------------- Launch ----------------

extern "C" void kernel_launch(void* const* d_in, const int* in_sizes, int n_in,
                              void* d_out, int out_size, void* d_ws, size_t ws_size,
                              hipStream_t stream) {
    const float* features = (const float*)d_in[0];
    const int*   edge_src = (const int*)d_in[1];
    const int*   edge_dst = (const int*)d_in[2];
    const float* edge_w   = (const float*)d_in[3];
    const float* Ws       = (const float*)d_in[4];
    const float* bs       = (const float*)d_in[5];
    const float* W_out    = (const float*)d_in[6];
    const float* b_out    = (const float*)d_in[7];

    const int N = in_sizes[0] / H;
    const int E = in_sizes[1];

    float* coords = (float*)d_out;
    float* feats  = coords + (size_t)N * 3;   // feats output region, used as accumulator

    char* wptr = (char*)d_ws;
    float* xbuf = (float*)wptr;  wptr += (size_t)N * H * sizeof(float);
    float* sup  = (float*)wptr;  wptr += (size_t)N * H * sizeof(float);
    int* row_ptr = (int*)wptr;   wptr += (size_t)(N + 1) * sizeof(int);
    int* cursor  = (int*)wptr;   wptr += (size_t)N * sizeof(int);
    int* ci      = (int*)wptr;   wptr += (size_t)E * sizeof(int);
    float* cw    = (float*)wptr; wptr += (size_t)E * sizeof(float);

    // --- build CSR (dst-indexed) ---
    hipMemsetAsync(cursor, 0, (size_t)N * sizeof(int), stream);
    hist_kernel<<<(E + 255) / 256, 256, 0, stream>>>(edge_dst, cursor, E);
    scan_kernel<<<1, 1024, 0, stream>>>(cursor, row_ptr, N);
    hipMemcpyAsync(cursor, row_ptr, (size_t)N * sizeof(int), hipMemcpyDeviceToDevice, stream);
    scatter_kernel<<<(E + 255) / 256, 256, 0, stream>>>(edge_src, edge_dst, edge_w,
                                                        cursor, ci, cw, E);

    dim3 ggrid((N + TILE - 1) / TILE, H / TILE, 1);

    // L0: x = relu(gcn(features, W0, b0))
    gemm_kernel<<<ggrid, 256, 0, stream>>>(features, Ws + 0 * HH, sup, N);
    spmm_kernel<<<N, H, 0, stream>>>(sup, row_ptr, ci, cw, bs + 0 * H, xbuf, nullptr, 0);
    // L1: feats = (features + relu(gcn(x, W1, b1))) / 2
    gemm_kernel<<<ggrid, 256, 0, stream>>>(xbuf, Ws + 1 * HH, sup, N);
    spmm_kernel<<<N, H, 0, stream>>>(sup, row_ptr, ci, cw, bs + 1 * H, feats, features, 1);

    // blocks 2-6
    for (int i = 2; i < 12; i += 2) {
        gemm_kernel<<<ggrid, 256, 0, stream>>>(feats, Ws + (size_t)i * HH, sup, N);
        spmm_kernel<<<N, H, 0, stream>>>(sup, row_ptr, ci, cw, bs + (size_t)i * H, xbuf, nullptr, 0);
        gemm_kernel<<<ggrid, 256, 0, stream>>>(xbuf, Ws + (size_t)(i + 1) * HH, sup, N);
        spmm_kernel<<<N, H, 0, stream>>>(sup, row_ptr, ci, cw, bs + (size_t)(i + 1) * H, feats, feats, 1);
    }

    // gc13
    gemm_kernel<<<ggrid, 256, 0, stream>>>(feats, Ws + 12 * (size_t)HH, sup, N);
    spmm_kernel<<<N, H, 0, stream>>>(sup, row_ptr, ci, cw, bs + 12 * H, feats, feats, 1);

    // head: coords = gcn(feats, W_out, b_out)   (no relu)
    gemm_head<<<(N + 255) / 256, 256, 0, stream>>>(feats, W_out, sup, N);
    spmm_head<<<(N + 255) / 256, 256, 0, stream>>>(sup, row_ptr, ci, cw, b_out, coords, N);
}

// Round 2
// 1219.804 us; speedup vs baseline: 1.4743x; 1.4743x over previous
//
#include <hip/hip_runtime.h>
#include <hip/hip_bf16.h>

#define H 192
#define HH (192*192)

typedef unsigned short u16;
typedef unsigned int u32;

__device__ __forceinline__ u16 f2bf(float f) {
    u32 u = __float_as_uint(f);
    u32 r = (u + 0x7FFFu + ((u >> 16) & 1u)) >> 16;   // RNE
    return (u16)r;
}

// ---------------- CSR construction ----------------

__global__ void hist_kernel(const int* __restrict__ dst, int* __restrict__ counts, int E) {
    int e = blockIdx.x * blockDim.x + threadIdx.x;
    if (e < E) atomicAdd(&counts[dst[e]], 1);
}

__global__ void scan_kernel(const int* __restrict__ counts, int* __restrict__ row_ptr, int n) {
    __shared__ int sh[1024];
    __shared__ int carry_s;
    int tid = threadIdx.x;
    if (tid == 0) carry_s = 0;
    __syncthreads();
    for (int base = 0; base < n; base += 1024) {
        int i = base + tid;
        int v = (i < n) ? counts[i] : 0;
        sh[tid] = v;
        __syncthreads();
        for (int off = 1; off < 1024; off <<= 1) {
            int t = (tid >= off) ? sh[tid - off] : 0;
            __syncthreads();
            sh[tid] += t;
            __syncthreads();
        }
        int carry = carry_s;
        if (i < n) row_ptr[i + 1] = carry + sh[tid];
        __syncthreads();
        if (tid == 1023) carry_s = carry + sh[1023];
        __syncthreads();
    }
    if (tid == 0) row_ptr[0] = 0;
}

__global__ void scatter_kernel(const int* __restrict__ src, const int* __restrict__ dst,
                               const float* __restrict__ w, int* __restrict__ cursor,
                               int* __restrict__ ci, float* __restrict__ cw, int E) {
    int e = blockIdx.x * blockDim.x + threadIdx.x;
    if (e < E) {
        int p = atomicAdd(&cursor[dst[e]], 1);
        ci[p] = src[e];
        cw[p] = w[e];
    }
}

// ---------------- Dense GEMM: S_bf16[M x 192] = A[M x 192] @ B[192 x 192] ----------------

#define TILE 64
#define KT 16

__global__ void gemm_kernel(const float* __restrict__ A, const float* __restrict__ B,
                            u16* __restrict__ C, int M) {
    __shared__ float As[KT][TILE + 1];
    __shared__ float Bs[KT][TILE + 1];
    int bm = blockIdx.x * TILE;
    int bn = blockIdx.y * TILE;
    int tid = threadIdx.x;          // 0..255
    int tr = tid >> 4, tc = tid & 15;
    float acc[4][4] = {};
    for (int k0 = 0; k0 < H; k0 += KT) {
        for (int i = tid; i < TILE * KT; i += 256) {
            int m = i / KT, kk = i % KT;
            int row = bm + m;
            As[kk][m] = (row < M) ? A[(size_t)row * H + k0 + kk] : 0.f;
        }
        for (int i = tid; i < KT * TILE; i += 256) {
            int kk = i / TILE, nn = i % TILE;
            Bs[kk][nn] = B[(size_t)(k0 + kk) * H + bn + nn];
        }
        __syncthreads();
        #pragma unroll
        for (int kk = 0; kk < KT; ++kk) {
            float a[4], b[4];
            #pragma unroll
            for (int i = 0; i < 4; i++) a[i] = As[kk][tr * 4 + i];
            #pragma unroll
            for (int j = 0; j < 4; j++) b[j] = Bs[kk][tc * 4 + j];
            #pragma unroll
            for (int i = 0; i < 4; i++)
                #pragma unroll
                for (int j = 0; j < 4; j++) acc[i][j] += a[i] * b[j];
        }
        __syncthreads();
    }
    for (int i = 0; i < 4; i++) {
        int row = bm + tr * 4 + i;
        if (row < M) {
            ushort4 p;
            p.x = f2bf(acc[i][0]); p.y = f2bf(acc[i][1]);
            p.z = f2bf(acc[i][2]); p.w = f2bf(acc[i][3]);
            *(ushort4*)&C[(size_t)row * H + bn + tc * 4] = p;
        }
    }
}

// ---------------- SpMM: out[v] = epilogue( sum_e w_e * S[src_e] + bias ) ----------------
// S is bf16 [N x 192]. 24 lanes per vertex, 8 cols/lane (one uint4 load/edge).
// mode 0: out = relu(agg + b)
// mode 1: out = (resid + relu(agg + b)) * 0.5

__device__ __forceinline__ void fma8(float acc[8], uint4 q, float w) {
    u32 u[4] = {q.x, q.y, q.z, q.w};
    #pragma unroll
    for (int i = 0; i < 4; i++) {
        float lo = __uint_as_float(u[i] << 16);
        float hi = __uint_as_float(u[i] & 0xFFFF0000u);
        acc[2*i]     += w * lo;
        acc[2*i + 1] += w * hi;
    }
}

__global__ void spmm_kernel(const u16* __restrict__ S, const int* __restrict__ rp,
                            const int* __restrict__ ci, const float* __restrict__ cw,
                            const float* __restrict__ bias, float* __restrict__ out,
                            const float* __restrict__ resid, int mode, int Nv) {
    int tid = threadIdx.x;               // 0..191
    int g = tid / 24;                    // vertex group 0..7
    int l = tid % 24;                    // lane within vertex
    int v = blockIdx.x * 8 + g;
    if (v >= Nv) return;
    int c0 = l * 8;                      // first of 8 owned columns
    float acc[8] = {};
    int beg = rp[v], end = rp[v + 1];
    const u16* Sc = S + c0;
    int e = beg;
    for (; e + 1 < end; e += 2) {
        int s0 = ci[e], s1 = ci[e + 1];
        float w0 = cw[e], w1 = cw[e + 1];
        uint4 q0 = *(const uint4*)(Sc + (size_t)s0 * H);
        uint4 q1 = *(const uint4*)(Sc + (size_t)s1 * H);
        fma8(acc, q0, w0);
        fma8(acc, q1, w1);
    }
    if (e < end) {
        int s0 = ci[e];
        float w0 = cw[e];
        uint4 q0 = *(const uint4*)(Sc + (size_t)s0 * H);
        fma8(acc, q0, w0);
    }
    size_t idx = (size_t)v * H + c0;
    float4 b0 = *(const float4*)&bias[c0];
    float4 b1 = *(const float4*)&bias[c0 + 4];
    float r[8] = {b0.x, b0.y, b0.z, b0.w, b1.x, b1.y, b1.z, b1.w};
    #pragma unroll
    for (int i = 0; i < 8; i++) acc[i] = fmaxf(acc[i] + r[i], 0.f);
    if (mode == 1) {
        float4 f0 = *(const float4*)&resid[idx];
        float4 f1 = *(const float4*)&resid[idx + 4];
        acc[0] = (acc[0] + f0.x) * 0.5f; acc[1] = (acc[1] + f0.y) * 0.5f;
        acc[2] = (acc[2] + f0.z) * 0.5f; acc[3] = (acc[3] + f0.w) * 0.5f;
        acc[4] = (acc[4] + f1.x) * 0.5f; acc[5] = (acc[5] + f1.y) * 0.5f;
        acc[6] = (acc[6] + f1.z) * 0.5f; acc[7] = (acc[7] + f1.w) * 0.5f;
    }
    float4 o0 = {acc[0], acc[1], acc[2], acc[3]};
    float4 o1 = {acc[4], acc[5], acc[6], acc[7]};
    *(float4*)&out[idx] = o0;
    *(float4*)&out[idx + 4] = o1;
}

// ---------------- Output head ----------------

__global__ void gemm_head(const float* __restrict__ A, const float* __restrict__ W,
                          float* __restrict__ S3, int M) {
    int row = blockIdx.x * blockDim.x + threadIdx.x;
    if (row >= M) return;
    float a0 = 0.f, a1 = 0.f, a2 = 0.f;
    for (int k = 0; k < H; k++) {
        float x = A[(size_t)row * H + k];
        a0 += x * W[k * 3 + 0];
        a1 += x * W[k * 3 + 1];
        a2 += x * W[k * 3 + 2];
    }
    S3[row * 3 + 0] = a0;
    S3[row * 3 + 1] = a1;
    S3[row * 3 + 2] = a2;
}

__global__ void spmm_head(const float* __restrict__ S3, const int* __restrict__ rp,
                          const int* __restrict__ ci, const float* __restrict__ cw,
                          const float* __restrict__ b_out, float* __restrict__ coords, int Nv) {
    int v = blockIdx.x * blockDim.x + threadIdx.x;
    if (v >= Nv) return;
    float a0 = b_out[0], a1 = b_out[1], a2 = b_out[2];
    int end = rp[v + 1];
    for (int e = rp[v]; e < end; ++e) {
        int s = ci[e];
        float w = cw[e];
        a0 += w * S3[s * 3 + 0];
        a1 += w * S3[s * 3 + 1];
        a2 += w * S3[s * 3 + 2];
    }
    coords[v * 3 + 0] = a0;
    coords[v * 3 + 1] = a1;
    coords[v * 3 + 2] = a2;
}

// ---------------- Launch ----------------

extern "C" void kernel_launch(void* const* d_in, const int* in_sizes, int n_in,
                              void* d_out, int out_size, void* d_ws, size_t ws_size,
                              hipStream_t stream) {
    const float* features = (const float*)d_in[0];
    const int*   edge_src = (const int*)d_in[1];
    const int*   edge_dst = (const int*)d_in[2];
    const float* edge_w   = (const float*)d_in[3];
    const float* Ws       = (const float*)d_in[4];
    const float* bs       = (const float*)d_in[5];
    const float* W_out    = (const float*)d_in[6];
    const float* b_out    = (const float*)d_in[7];

    const int N = in_sizes[0] / H;
    const int E = in_sizes[1];

    float* coords = (float*)d_out;
    float* feats  = coords + (size_t)N * 3;   // feats output region, used as accumulator

    char* wptr = (char*)d_ws;
    float* xbuf = (float*)wptr;  wptr += (size_t)N * H * sizeof(float);
    u16*   sup  = (u16*)wptr;    wptr += (size_t)N * H * sizeof(u16);
    float* S3   = (float*)wptr;  wptr += (size_t)N * 3 * sizeof(float);
    int* row_ptr = (int*)wptr;   wptr += (size_t)(N + 1) * sizeof(int);
    int* cursor  = (int*)wptr;   wptr += (size_t)N * sizeof(int);
    int* ci      = (int*)wptr;   wptr += (size_t)E * sizeof(int);
    float* cw    = (float*)wptr; wptr += (size_t)E * sizeof(float);

    // --- build CSR (dst-indexed) ---
    hipMemsetAsync(cursor, 0, (size_t)N * sizeof(int), stream);
    hist_kernel<<<(E + 255) / 256, 256, 0, stream>>>(edge_dst, cursor, E);
    scan_kernel<<<1, 1024, 0, stream>>>(cursor, row_ptr, N);
    hipMemcpyAsync(cursor, row_ptr, (size_t)N * sizeof(int), hipMemcpyDeviceToDevice, stream);
    scatter_kernel<<<(E + 255) / 256, 256, 0, stream>>>(edge_src, edge_dst, edge_w,
                                                        cursor, ci, cw, E);

    dim3 ggrid((N + TILE - 1) / TILE, H / TILE, 1);
    int sgrid = (N + 7) / 8;

    // L0: x = relu(gcn(features, W0, b0))
    gemm_kernel<<<ggrid, 256, 0, stream>>>(features, Ws + 0 * HH, sup, N);
    spmm_kernel<<<sgrid, 192, 0, stream>>>(sup, row_ptr, ci, cw, bs + 0 * H, xbuf, nullptr, 0, N);
    // L1: feats = (features + relu(gcn(x, W1, b1))) / 2
    gemm_kernel<<<ggrid, 256, 0, stream>>>(xbuf, Ws + 1 * HH, sup, N);
    spmm_kernel<<<sgrid, 192, 0, stream>>>(sup, row_ptr, ci, cw, bs + 1 * H, feats, features, 1, N);

    // blocks 2-6
    for (int i = 2; i < 12; i += 2) {
        gemm_kernel<<<ggrid, 256, 0, stream>>>(feats, Ws + (size_t)i * HH, sup, N);
        spmm_kernel<<<sgrid, 192, 0, stream>>>(sup, row_ptr, ci, cw, bs + (size_t)i * H, xbuf, nullptr, 0, N);
        gemm_kernel<<<ggrid, 256, 0, stream>>>(xbuf, Ws + (size_t)(i + 1) * HH, sup, N);
        spmm_kernel<<<sgrid, 192, 0, stream>>>(sup, row_ptr, ci, cw, bs + (size_t)(i + 1) * H, feats, feats, 1, N);
    }

    // gc13
    gemm_kernel<<<ggrid, 256, 0, stream>>>(feats, Ws + 12 * (size_t)HH, sup, N);
    spmm_kernel<<<sgrid, 192, 0, stream>>>(sup, row_ptr, ci, cw, bs + 12 * H, feats, feats, 1, N);

    // head: coords = gcn(feats, W_out, b_out)   (no relu)
    gemm_head<<<(N + 255) / 256, 256, 0, stream>>>(feats, W_out, S3, N);
    spmm_head<<<(N + 255) / 256, 256, 0, stream>>>(S3, row_ptr, ci, cw, b_out, coords, N);
}

// Round 3
// 1092.537 us; speedup vs baseline: 1.6461x; 1.1165x over previous
//
#include <hip/hip_runtime.h>
#include <hip/hip_bf16.h>

#define H 192
#define HH (192*192)
#define NLAYER 13

typedef unsigned short u16;
typedef unsigned int u32;

typedef __attribute__((ext_vector_type(8))) short short8;
typedef __attribute__((ext_vector_type(4))) float floatx4;

__device__ __forceinline__ u16 f2bf(float f) {
    u32 u = __float_as_uint(f);
    u32 r = (u + 0x7FFFu + ((u >> 16) & 1u)) >> 16;   // RNE
    return (u16)r;
}
__device__ __forceinline__ float bf2f(u16 h) {
    return __uint_as_float(((u32)h) << 16);
}

// ---------------- CSR construction ----------------

__global__ void hist_kernel(const int* __restrict__ dst, int* __restrict__ counts, int E) {
    int e = blockIdx.x * blockDim.x + threadIdx.x;
    if (e < E) atomicAdd(&counts[dst[e]], 1);
}

__global__ void scan_kernel(const int* __restrict__ counts, int* __restrict__ row_ptr, int n) {
    __shared__ int sh[1024];
    __shared__ int carry_s;
    int tid = threadIdx.x;
    if (tid == 0) carry_s = 0;
    __syncthreads();
    for (int base = 0; base < n; base += 1024) {
        int i = base + tid;
        int v = (i < n) ? counts[i] : 0;
        sh[tid] = v;
        __syncthreads();
        for (int off = 1; off < 1024; off <<= 1) {
            int t = (tid >= off) ? sh[tid - off] : 0;
            __syncthreads();
            sh[tid] += t;
            __syncthreads();
        }
        int carry = carry_s;
        if (i < n) row_ptr[i + 1] = carry + sh[tid];
        __syncthreads();
        if (tid == 1023) carry_s = carry + sh[1023];
        __syncthreads();
    }
    if (tid == 0) row_ptr[0] = 0;
}

__global__ void scatter_kernel(const int* __restrict__ src, const int* __restrict__ dst,
                               const float* __restrict__ w, int* __restrict__ cursor,
                               int* __restrict__ ci, float* __restrict__ cw, int E) {
    int e = blockIdx.x * blockDim.x + threadIdx.x;
    if (e < E) {
        int p = atomicAdd(&cursor[dst[e]], 1);
        ci[p] = src[e];
        cw[p] = w[e];
    }
}

// ---------------- Weight prep: Wt_hi/Wt_lo[l][n][k] = split(W[l][k][n]) ----------------

__global__ void wprep_kernel(const float* __restrict__ W, u16* __restrict__ Wt_hi,
                             u16* __restrict__ Wt_lo, int total) {
    int idx = blockIdx.x * blockDim.x + threadIdx.x;
    if (idx >= total) return;
    int l = idx / HH;
    int rem = idx - l * HH;
    int k = rem / H;
    int n = rem - k * H;
    float v = W[(size_t)l * HH + (size_t)k * H + n];
    u16 hi = f2bf(v);
    float res = v - bf2f(hi);
    u16 lo = f2bf(res);
    size_t o = (size_t)l * HH + (size_t)n * H + k;
    Wt_hi[o] = hi;
    Wt_lo[o] = lo;
}

// ---------------- features fp32 -> bf16 ----------------

__global__ void conv_kernel(const float* __restrict__ in, u16* __restrict__ out, int total4) {
    int idx = blockIdx.x * blockDim.x + threadIdx.x;
    if (idx >= total4) return;
    float4 v = ((const float4*)in)[idx];
    ushort4 p;
    p.x = f2bf(v.x); p.y = f2bf(v.y); p.z = f2bf(v.z); p.w = f2bf(v.w);
    ((ushort4*)out)[idx] = p;
}

// ---------------- MFMA GEMM: C_bf16[M x 192] = A_bf16[M x 192] @ (W_hi + W_lo) ----------------
// Wt_* stored transposed [n][k]. Wave = 16-row chunk x 6 n-tiles (half of 12).
// A-frag: lane holds A[rm + (lane&15)][quad*8 + j], j=0..7 (16B contiguous).
// B-frag: lane holds Wt[nt*16 + (lane&15)][quad*8 + j] (16B contiguous).
// C/D:    col = lane&15, row = quad*4 + reg.

__global__ __launch_bounds__(256) void mfma_gemm(
    const u16* __restrict__ A, const u16* __restrict__ Wt_hi, const u16* __restrict__ Wt_lo,
    u16* __restrict__ C, int M)
{
    int wave = threadIdx.x >> 6;
    int lane = threadIdx.x & 63;
    int gw = blockIdx.x * 4 + wave;
    int chunk = gw >> 1;
    int half = gw & 1;
    int rm = chunk * 16;
    if (rm >= M) return;
    int col = lane & 15;
    int quad = lane >> 4;

    int arow = rm + col;
    if (arow >= M) arow = M - 1;
    const u16* Ap = A + (size_t)arow * H + quad * 8;
    short8 a[6];
    #pragma unroll
    for (int k = 0; k < 6; k++) a[k] = *(const short8*)(Ap + k * 32);

    floatx4 acc[6];
    int nb = half * 6;
    #pragma unroll
    for (int nt = 0; nt < 6; nt++) {
        int n = (nb + nt) * 16 + col;
        const u16* Bh = Wt_hi + (size_t)n * H + quad * 8;
        const u16* Bl = Wt_lo + (size_t)n * H + quad * 8;
        floatx4 c = {0.f, 0.f, 0.f, 0.f};
        #pragma unroll
        for (int k = 0; k < 6; k++) {
            short8 bh = *(const short8*)(Bh + k * 32);
            short8 bl = *(const short8*)(Bl + k * 32);
            c = __builtin_amdgcn_mfma_f32_16x16x32_bf16(a[k], bh, c, 0, 0, 0);
            c = __builtin_amdgcn_mfma_f32_16x16x32_bf16(a[k], bl, c, 0, 0, 0);
        }
        acc[nt] = c;
    }
    #pragma unroll
    for (int nt = 0; nt < 6; nt++) {
        int n = (nb + nt) * 16 + col;
        #pragma unroll
        for (int r = 0; r < 4; r++) {
            int row = rm + quad * 4 + r;
            if (row < M) C[(size_t)row * H + n] = f2bf(acc[nt][r]);
        }
    }
}

// ---------------- SpMM: 24 lanes/vertex, 8 cols/lane, uint4 gathers of bf16 rows ----------
// mode 0: out_bf = bf16(relu(agg + b))
// mode 1: out_f32 = (resid + relu(agg + b)) * 0.5 ; out_bf = bf16(out_f32)

__device__ __forceinline__ void fma8(float acc[8], uint4 q, float w) {
    u32 u[4] = {q.x, q.y, q.z, q.w};
    #pragma unroll
    for (int i = 0; i < 4; i++) {
        float lo = __uint_as_float(u[i] << 16);
        float hi = __uint_as_float(u[i] & 0xFFFF0000u);
        acc[2*i]     += w * lo;
        acc[2*i + 1] += w * hi;
    }
}

__global__ void spmm_kernel(const u16* __restrict__ S, const int* __restrict__ rp,
                            const int* __restrict__ ci, const float* __restrict__ cw,
                            const float* __restrict__ bias, float* __restrict__ out,
                            u16* __restrict__ out_bf, const float* __restrict__ resid,
                            int mode, int Nv) {
    int tid = threadIdx.x;               // 0..191
    int g = tid / 24;
    int l = tid % 24;
    int v = blockIdx.x * 8 + g;
    if (v >= Nv) return;
    int c0 = l * 8;
    float acc[8] = {};
    int beg = rp[v], end = rp[v + 1];
    const u16* Sc = S + c0;
    int e = beg;
    for (; e + 1 < end; e += 2) {
        int s0 = ci[e], s1 = ci[e + 1];
        float w0 = cw[e], w1 = cw[e + 1];
        uint4 q0 = *(const uint4*)(Sc + (size_t)s0 * H);
        uint4 q1 = *(const uint4*)(Sc + (size_t)s1 * H);
        fma8(acc, q0, w0);
        fma8(acc, q1, w1);
    }
    if (e < end) {
        uint4 q0 = *(const uint4*)(Sc + (size_t)ci[e] * H);
        fma8(acc, q0, cw[e]);
    }
    size_t idx = (size_t)v * H + c0;
    float4 b0 = *(const float4*)&bias[c0];
    float4 b1 = *(const float4*)&bias[c0 + 4];
    float r[8] = {b0.x, b0.y, b0.z, b0.w, b1.x, b1.y, b1.z, b1.w};
    #pragma unroll
    for (int i = 0; i < 8; i++) acc[i] = fmaxf(acc[i] + r[i], 0.f);
    if (mode == 1) {
        float4 f0 = *(const float4*)&resid[idx];
        float4 f1 = *(const float4*)&resid[idx + 4];
        acc[0] = (acc[0] + f0.x) * 0.5f; acc[1] = (acc[1] + f0.y) * 0.5f;
        acc[2] = (acc[2] + f0.z) * 0.5f; acc[3] = (acc[3] + f0.w) * 0.5f;
        acc[4] = (acc[4] + f1.x) * 0.5f; acc[5] = (acc[5] + f1.y) * 0.5f;
        acc[6] = (acc[6] + f1.z) * 0.5f; acc[7] = (acc[7] + f1.w) * 0.5f;
        float4 o0 = {acc[0], acc[1], acc[2], acc[3]};
        float4 o1 = {acc[4], acc[5], acc[6], acc[7]};
        *(float4*)&out[idx] = o0;
        *(float4*)&out[idx + 4] = o1;
    }
    ushort4 p0, p1;
    p0.x = f2bf(acc[0]); p0.y = f2bf(acc[1]); p0.z = f2bf(acc[2]); p0.w = f2bf(acc[3]);
    p1.x = f2bf(acc[4]); p1.y = f2bf(acc[5]); p1.z = f2bf(acc[6]); p1.w = f2bf(acc[7]);
    *(ushort4*)&out_bf[idx] = p0;
    *(ushort4*)&out_bf[idx + 4] = p1;
}

// ---------------- Output head (fp32, reads fp32 feats) ----------------

__global__ void gemm_head(const float* __restrict__ A, const float* __restrict__ W,
                          float* __restrict__ S3, int M) {
    int row = blockIdx.x * blockDim.x + threadIdx.x;
    if (row >= M) return;
    float a0 = 0.f, a1 = 0.f, a2 = 0.f;
    for (int k = 0; k < H; k++) {
        float x = A[(size_t)row * H + k];
        a0 += x * W[k * 3 + 0];
        a1 += x * W[k * 3 + 1];
        a2 += x * W[k * 3 + 2];
    }
    S3[row * 3 + 0] = a0;
    S3[row * 3 + 1] = a1;
    S3[row * 3 + 2] = a2;
}

__global__ void spmm_head(const float* __restrict__ S3, const int* __restrict__ rp,
                          const int* __restrict__ ci, const float* __restrict__ cw,
                          const float* __restrict__ b_out, float* __restrict__ coords, int Nv) {
    int v = blockIdx.x * blockDim.x + threadIdx.x;
    if (v >= Nv) return;
    float a0 = b_out[0], a1 = b_out[1], a2 = b_out[2];
    int end = rp[v + 1];
    for (int e = rp[v]; e < end; ++e) {
        int s = ci[e];
        float w = cw[e];
        a0 += w * S3[s * 3 + 0];
        a1 += w * S3[s * 3 + 1];
        a2 += w * S3[s * 3 + 2];
    }
    coords[v * 3 + 0] = a0;
    coords[v * 3 + 1] = a1;
    coords[v * 3 + 2] = a2;
}

// ---------------- Launch ----------------

extern "C" void kernel_launch(void* const* d_in, const int* in_sizes, int n_in,
                              void* d_out, int out_size, void* d_ws, size_t ws_size,
                              hipStream_t stream) {
    const float* features = (const float*)d_in[0];
    const int*   edge_src = (const int*)d_in[1];
    const int*   edge_dst = (const int*)d_in[2];
    const float* edge_w   = (const float*)d_in[3];
    const float* Ws       = (const float*)d_in[4];
    const float* bs       = (const float*)d_in[5];
    const float* W_out    = (const float*)d_in[6];
    const float* b_out    = (const float*)d_in[7];

    const int N = in_sizes[0] / H;
    const int E = in_sizes[1];

    float* coords = (float*)d_out;
    float* feats  = coords + (size_t)N * 3;   // fp32 feats output/accumulator

    char* wptr = (char*)d_ws;
    u16* xbuf_bf  = (u16*)wptr;   wptr += (size_t)N * H * sizeof(u16);  // also holds bf16 features initially
    u16* sup      = (u16*)wptr;   wptr += (size_t)N * H * sizeof(u16);
    u16* feats_bf = (u16*)wptr;   wptr += (size_t)N * H * sizeof(u16);
    u16* Wt_hi    = (u16*)wptr;   wptr += (size_t)NLAYER * HH * sizeof(u16);
    u16* Wt_lo    = (u16*)wptr;   wptr += (size_t)NLAYER * HH * sizeof(u16);
    float* S3     = (float*)wptr; wptr += (size_t)N * 3 * sizeof(float);
    int* row_ptr  = (int*)wptr;   wptr += (size_t)(N + 1) * sizeof(int);
    int* cursor   = (int*)wptr;   wptr += (size_t)N * sizeof(int);
    int* ci       = (int*)wptr;   wptr += (size_t)E * sizeof(int);
    float* cw     = (float*)wptr; wptr += (size_t)E * sizeof(float);

    // --- build CSR (dst-indexed) ---
    hipMemsetAsync(cursor, 0, (size_t)N * sizeof(int), stream);
    hist_kernel<<<(E + 255) / 256, 256, 0, stream>>>(edge_dst, cursor, E);
    scan_kernel<<<1, 1024, 0, stream>>>(cursor, row_ptr, N);
    hipMemcpyAsync(cursor, row_ptr, (size_t)N * sizeof(int), hipMemcpyDeviceToDevice, stream);
    scatter_kernel<<<(E + 255) / 256, 256, 0, stream>>>(edge_src, edge_dst, edge_w,
                                                        cursor, ci, cw, E);

    // --- weight split/transpose + feature conversion ---
    int wtotal = NLAYER * HH;
    wprep_kernel<<<(wtotal + 255) / 256, 256, 0, stream>>>(Ws, Wt_hi, Wt_lo, wtotal);
    int c4 = N * H / 4;
    conv_kernel<<<(c4 + 255) / 256, 256, 0, stream>>>(features, xbuf_bf, c4);

    int gwaves = 2 * ((N + 15) / 16);
    int gblocks = (gwaves + 3) / 4;
    int sgrid = (N + 7) / 8;

    // L0: x = relu(gcn(features, W0, b0))       [xbuf_bf holds bf16 features; overwritten after gemm]
    mfma_gemm<<<gblocks, 256, 0, stream>>>(xbuf_bf, Wt_hi + 0 * HH, Wt_lo + 0 * HH, sup, N);
    spmm_kernel<<<sgrid, 192, 0, stream>>>(sup, row_ptr, ci, cw, bs + 0 * H, nullptr, xbuf_bf, nullptr, 0, N);
    // L1: feats = (features + relu(gcn(x, W1, b1))) / 2
    mfma_gemm<<<gblocks, 256, 0, stream>>>(xbuf_bf, Wt_hi + 1 * HH, Wt_lo + 1 * HH, sup, N);
    spmm_kernel<<<sgrid, 192, 0, stream>>>(sup, row_ptr, ci, cw, bs + 1 * H, feats, feats_bf, features, 1, N);

    // blocks 2-6
    for (int i = 2; i < 12; i += 2) {
        mfma_gemm<<<gblocks, 256, 0, stream>>>(feats_bf, Wt_hi + (size_t)i * HH, Wt_lo + (size_t)i * HH, sup, N);
        spmm_kernel<<<sgrid, 192, 0, stream>>>(sup, row_ptr, ci, cw, bs + (size_t)i * H, nullptr, xbuf_bf, nullptr, 0, N);
        mfma_gemm<<<gblocks, 256, 0, stream>>>(xbuf_bf, Wt_hi + (size_t)(i+1) * HH, Wt_lo + (size_t)(i+1) * HH, sup, N);
        spmm_kernel<<<sgrid, 192, 0, stream>>>(sup, row_ptr, ci, cw, bs + (size_t)(i+1) * H, feats, feats_bf, feats, 1, N);
    }

    // gc13
    mfma_gemm<<<gblocks, 256, 0, stream>>>(feats_bf, Wt_hi + 12 * (size_t)HH, Wt_lo + 12 * (size_t)HH, sup, N);
    spmm_kernel<<<sgrid, 192, 0, stream>>>(sup, row_ptr, ci, cw, bs + 12 * H, feats, feats_bf, feats, 1, N);

    // head: coords = gcn(feats, W_out, b_out)   (no relu)
    gemm_head<<<(N + 255) / 256, 256, 0, stream>>>(feats, W_out, S3, N);
    spmm_head<<<(N + 255) / 256, 256, 0, stream>>>(S3, row_ptr, ci, cw, b_out, coords, N);
}